// Round 1
// baseline (246.063 us; speedup 1.0000x reference)
//
#include <hip/hip_runtime.h>
#include <stdint.h>
#include <math.h>

// Problem constants: B=4, S=2048, D=1024
// Pipeline (4 dispatches): cvt(+zero l) -> qkv -> scores(exp epilogue + atomic rowsum)
//                          -> pv(normalize by 1/l).
// qkv_gemm rewritten this round: 256x256 tile, 8 waves (512 thr), BK=64, double-buffered
// 128 KiB LDS, 4 sub-phases per K-tile with raw s_barrier (no waitcnt drain), vmcnt(0)
// only at the K-tile boundary (T3+T4), setprio around MFMA (T5). Fragment layout and
// XOR chunk swizzle identical to the verified 128^2 version (stage-side and read-side
// XOR are the same involution; conflict-free verified earlier).
// scores/pv/cvt unchanged from the verified previous version.
#define BK 64
#define LSTR 64   // main-loop LDS row stride (bf16 elems)
#define ETS 132   // epilogue tile stride for 128-tiles (128 + 4 pad)
#define QTILE 16384  // 256x64 bf16 tile in ushorts (32 KiB)

typedef __attribute__((ext_vector_type(8))) short short8;
typedef __attribute__((ext_vector_type(16))) float floatx16;

typedef __attribute__((address_space(3))) unsigned int lds_u32;
typedef const __attribute__((address_space(1))) unsigned int glb_u32;

__device__ __forceinline__ unsigned short f2bf(float f) {
    union { float f; unsigned u; } x; x.f = f;
    unsigned r = x.u + 0x7fffu + ((x.u >> 16) & 1u);  // RNE
    return (unsigned short)(r >> 16);
}

// ---------------- kernel 1: fp32 -> bf16 convert + zero the l[] accumulator ----------------
__global__ void cvt_kernel(const float* __restrict__ x,
                           const float* __restrict__ wq,
                           const float* __restrict__ wk,
                           const float* __restrict__ wv,
                           unsigned short* __restrict__ xb,
                           unsigned short* __restrict__ wb,
                           float* __restrict__ lsum) {
    int i4 = (blockIdx.x * 256 + threadIdx.x) * 4;   // total 11534336 elems, exact grid
    if (blockIdx.x < 8) {                            // zero l[8192] (atomic target in scores)
        float4 z = (float4){0.f, 0.f, 0.f, 0.f};
        *(float4*)(lsum + i4) = z;
    }
    const float* src; unsigned short* dst; int off;
    if (i4 < 8388608)       { src = x;  dst = xb;            off = i4; }
    else if (i4 < 9437184)  { src = wq; dst = wb;            off = i4 - 8388608; }
    else if (i4 < 10485760) { src = wk; dst = wb + 1048576;  off = i4 - 9437184; }
    else                    { src = wv; dst = wb + 2097152;  off = i4 - 10485760; }
    float4 v = *(const float4*)(src + off);
    ushort4 o;
    o.x = f2bf(v.x); o.y = f2bf(v.y); o.z = f2bf(v.z); o.w = f2bf(v.w);
    *(ushort4*)(dst + off) = o;
}

// ---------------- shared GEMM pieces (128^2 path, used by scores/pv) ----------------
// async-stage a 128x64 bf16 tile (row-major, ld elems) into unpadded LDS with XOR
// swizzle: LDS chunk (row, cc) holds global chunk (row, cc ^ (row&7)).
__device__ __forceinline__ void stage_async(unsigned short* sh, const unsigned short* g,
                                            int ld, int tid) {
#pragma unroll
    for (int it = 0; it < 4; ++it) {
        int c = it * 256 + tid;          // 1024 chunks of 16B
        int row = c >> 3, cc = c & 7;
        int gcc = cc ^ (row & 7);
        __builtin_amdgcn_global_load_lds(
            (glb_u32*)(g + (size_t)row * ld + gcc * 8),
            (lds_u32*)(sh + c * 8), 16, 0, 0);
    }
}

// one BK=64 step: 8 MFMAs (32x32x16) per wave, 4 k-substeps of 16.
// A-frag: lane holds A[m = lane&31][k = (lane>>5)*8 + j]; B^T-pattern identical.
// Fragment reads un-swizzle the staging XOR.
__device__ __forceinline__ void mfma_step(const unsigned short* Ash, const unsigned short* Bsh,
                                          int lane, int wr, int wc, floatx16 acc[2][2]) {
    int lm = lane & 31, lg = lane >> 5;
#pragma unroll
    for (int h = 0; h < 4; ++h) {
        short8 af[2], bf[2];
#pragma unroll
        for (int i = 0; i < 2; ++i) {
            int ar = wr * 64 + i * 32 + lm;
            int br = wc * 64 + i * 32 + lm;
            af[i] = *(const short8*)(Ash + ar * LSTR + (((h << 1) | lg) ^ (ar & 7)) * 8);
            bf[i] = *(const short8*)(Bsh + br * LSTR + (((h << 1) | lg) ^ (br & 7)) * 8);
        }
#pragma unroll
        for (int i = 0; i < 2; ++i)
#pragma unroll
            for (int j = 0; j < 2; ++j)
                acc[i][j] = __builtin_amdgcn_mfma_f32_32x32x16_bf16(af[i], bf[j], acc[i][j], 0, 0, 0);
    }
}

#define ACC_ZERO {0.f,0.f,0.f,0.f,0.f,0.f,0.f,0.f,0.f,0.f,0.f,0.f,0.f,0.f,0.f,0.f}

// C/D layout (verified m74/m101): col = lane&31, row = (reg&3) + 8*(reg>>2) + 4*(lane>>5)

// ---------------- kernel 2: fused QKV projection GEMM (256^2 8-wave pipelined) -------------
// C[m,n] = sum_k Xb[m,k] * Wb[n,k], m in [0,8192), n in [0,3072), K=1024
// bn>>2: 0=Q row-major, 1=K row-major, 2=V TRANSPOSED Vt[b][d][s].
// stage a 256x64 tile (2048 chunks of 16B) with 512 threads, same XOR chunk swizzle.
__device__ __forceinline__ void stage256(unsigned short* sh, const unsigned short* g, int tid) {
#pragma unroll
    for (int it = 0; it < 4; ++it) {
        int c = it * 512 + tid;          // 2048 chunks of 16B
        int row = c >> 3, cc = c & 7;
        int gcc = cc ^ (row & 7);
        __builtin_amdgcn_global_load_lds(
            (glb_u32*)(g + (size_t)row * 1024 + gcc * 8),
            (lds_u32*)(sh + c * 8), 16, 0, 0);
    }
}

__global__ __launch_bounds__(512, 2) void qkv_gemm(const unsigned short* __restrict__ Xb,
                                                   const unsigned short* __restrict__ Wb,
                                                   unsigned short* __restrict__ Qb,
                                                   unsigned short* __restrict__ Kb,
                                                   unsigned short* __restrict__ Vt) {
    // [A buf0][A buf1][B buf0][B buf1], each 256x64 bf16 = 32 KiB -> 128 KiB total
    __shared__ unsigned short lds[4 * QTILE];
    int tid = threadIdx.x;
    int bm = blockIdx.x, bn = blockIdx.y;      // 32 x 12
    int lane = tid & 63, w = tid >> 6;
    int wm = w >> 2, wn = w & 3;               // 2 x 4 waves; per-wave C = 128x64
    int lm = lane & 31, lg = lane >> 5;
    int xr = lm & 7;                            // swizzle key (rows are 32-aligned per frag)

    floatx16 acc[4][2];
#pragma unroll
    for (int mi = 0; mi < 4; ++mi)
#pragma unroll
        for (int nj = 0; nj < 2; ++nj)
            acc[mi][nj] = (floatx16)0.f;

    // per-thread fragment row offsets (elements)
    int aoff[4], boff[2];
#pragma unroll
    for (int mi = 0; mi < 4; ++mi) aoff[mi] = (wm * 128 + mi * 32 + lm) * LSTR;
#pragma unroll
    for (int nj = 0; nj < 2; ++nj) boff[nj] = (wn * 64 + nj * 32 + lm) * LSTR;

    const unsigned short* Ag = Xb + (size_t)bm * 256 * 1024;
    const unsigned short* Bg = Wb + (size_t)bn * 256 * 1024;

    // prologue: stage K-tile 0 into buffer 0, drain, one barrier
    stage256(lds, Ag, tid);
    stage256(lds + 2 * QTILE, Bg, tid);
    asm volatile("s_waitcnt vmcnt(0)" ::: "memory");
    __builtin_amdgcn_s_barrier();
    __builtin_amdgcn_sched_barrier(0);

    int cur = 0;
#pragma unroll 2
    for (int t = 0; t < 16; ++t) {
        const unsigned short* Ash = lds + cur * QTILE;
        const unsigned short* Bsh = lds + 2 * QTILE + cur * QTILE;
        // issue next-tile stages first: 8 global_load_lds stay in flight across the
        // 4 phases below (never drained mid-tile)
        if (t < 15) {
            stage256(lds + (cur ^ 1) * QTILE, Ag + (t + 1) * BK, tid);
            stage256(lds + 2 * QTILE + (cur ^ 1) * QTILE, Bg + (t + 1) * BK, tid);
        }
        // 4 phases of {6 ds_read_b128 ; barrier ; 8 MFMA ; barrier}
#pragma unroll
        for (int h = 0; h < 4; ++h) {
            int co = ((((h << 1) | lg) ^ xr)) << 3;
            short8 af[4], bf[2];
#pragma unroll
            for (int mi = 0; mi < 4; ++mi)
                af[mi] = *(const short8*)(Ash + aoff[mi] + co);
#pragma unroll
            for (int nj = 0; nj < 2; ++nj)
                bf[nj] = *(const short8*)(Bsh + boff[nj] + co);
            __builtin_amdgcn_s_barrier();
            __builtin_amdgcn_s_setprio(1);
#pragma unroll
            for (int mi = 0; mi < 4; ++mi)
#pragma unroll
                for (int nj = 0; nj < 2; ++nj)
                    acc[mi][nj] = __builtin_amdgcn_mfma_f32_32x32x16_bf16(af[mi], bf[nj], acc[mi][nj], 0, 0, 0);
            __builtin_amdgcn_s_setprio(0);
            if (h < 3) __builtin_amdgcn_s_barrier();
        }
        // K-tile boundary: my 8 prefetch loads (issued ~4 phases ago) must have landed;
        // barrier publishes them to all waves. sched_barrier pins next-tile ds_reads after.
        if (t < 15) { asm volatile("s_waitcnt vmcnt(0)" ::: "memory"); }
        __builtin_amdgcn_s_barrier();
        __builtin_amdgcn_sched_barrier(0);
        cur ^= 1;
    }

    // ---------------- epilogue: repack through LDS (overlays the operand buffers) ----------
    int which = bn >> 2;               // 0=Q 1=K 2=V
    int nnb = (bn & 3) << 8;           // 256-col chunk within the 1024-wide output
    unsigned short* ep = lds;
    const int EPS = 136;               // 128 cols + 8 pad (16B-aligned rows: 272 = 16*17)
    if (which < 2) {
        // row-major [m][n]; two 128-col chunks, chunk c written by waves with wn>>1 == c
        unsigned short* gq = (which == 0 ? Qb : Kb) + (size_t)bm * 256 * 1024 + nnb;
#pragma unroll
        for (int c = 0; c < 2; ++c) {
            __syncthreads();
            if ((wn >> 1) == c) {
                int colb = (wn & 1) * 64;
#pragma unroll
                for (int mi = 0; mi < 4; ++mi)
#pragma unroll
                    for (int nj = 0; nj < 2; ++nj)
#pragma unroll
                        for (int p = 0; p < 16; ++p) {
                            int m = wm * 128 + mi * 32 + (p & 3) + 8 * (p >> 2) + 4 * lg;
                            ep[m * EPS + colb + nj * 32 + lm] = f2bf(acc[mi][nj][p]);
                        }
            }
            __syncthreads();
#pragma unroll
            for (int it = 0; it < 8; ++it) {
                int m = it * 32 + (tid >> 4), cg = tid & 15;
                *(uint4*)(gq + (size_t)m * 1024 + c * 128 + cg * 8) =
                    *(const uint4*)(ep + m * EPS + cg * 8);
            }
        }
    } else {
        // V transposed: Vt[b][d][s]; two 128-wide m(s)-chunks, chunk c written by wm==c.
        // reg groups 4g..4g+3 are 4 consecutive m-rows at fixed col -> ushort4 along s.
        unsigned short* gv = Vt + ((size_t)(bm >> 3) * 1024 + nnb) * 2048 + (bm & 7) * 256;
#pragma unroll
        for (int c = 0; c < 2; ++c) {
            __syncthreads();
            if (wm == c) {
#pragma unroll
                for (int mi = 0; mi < 4; ++mi)
#pragma unroll
                    for (int nj = 0; nj < 2; ++nj) {
                        int n = wn * 64 + nj * 32 + lm;
#pragma unroll
                        for (int g = 0; g < 4; ++g) {
                            int mloc = mi * 32 + 8 * g + 4 * lg;
                            ushort4 o;
                            o.x = f2bf(acc[mi][nj][4 * g + 0]); o.y = f2bf(acc[mi][nj][4 * g + 1]);
                            o.z = f2bf(acc[mi][nj][4 * g + 2]); o.w = f2bf(acc[mi][nj][4 * g + 3]);
                            *(ushort4*)(ep + n * EPS + mloc) = o;
                        }
                    }
            }
            __syncthreads();
#pragma unroll
            for (int it = 0; it < 8; ++it) {
                int n = it * 32 + (tid >> 4), mg = tid & 15;
                *(uint4*)(gv + (size_t)n * 2048 + c * 128 + mg * 8) =
                    *(const uint4*)(ep + n * EPS + mg * 8);
            }
        }
    }
}

// ---------------- kernel 3: P' = exp((Q K^T)/32) masked, bf16, + row sums l[] --------------
// Lower-tri tiles only; unnormalized exp (|s| <~ 8 so fp32-safe, softmax is shift-invariant).
__global__ __launch_bounds__(256) void scores_gemm(const unsigned short* __restrict__ Qb,
                                                   const unsigned short* __restrict__ Kb,
                                                   const int* __restrict__ mask,
                                                   unsigned short* __restrict__ Pb,
                                                   float* __restrict__ lsum) {
    int u = blockIdx.x, b = blockIdx.y;
    int ti = (int)((sqrtf(8.0f * (float)u + 1.0f) - 1.0f) * 0.5f);
    while ((ti + 1) * (ti + 2) / 2 <= u) ti++;
    while (ti * (ti + 1) / 2 > u) ti--;
    int tj = u - ti * (ti + 1) / 2;

    __shared__ unsigned short shbuf[128 * ETS];
    unsigned short* Ash = shbuf;
    unsigned short* Bsh = shbuf + 128 * LSTR;
    int tid = threadIdx.x;
    int lane = tid & 63, w = tid >> 6, wr = w >> 1, wc = w & 1;
    floatx16 acc[2][2] = {{ACC_ZERO, ACC_ZERO}, {ACC_ZERO, ACC_ZERO}};

    const unsigned short* Ag = Qb + ((size_t)b * 2048 + ti * 128) * 1024;
    const unsigned short* Bg = Kb + ((size_t)b * 2048 + tj * 128) * 1024;
    for (int k0 = 0; k0 < 1024; k0 += BK) {
        __syncthreads();
        stage_async(Ash, Ag + k0, 1024, tid);
        stage_async(Bsh, Bg + k0, 1024, tid);
        __syncthreads();
        mfma_step(Ash, Bsh, lane, wr, wc, acc);
    }

    int lm = lane & 31, lg = lane >> 5;
    int mk[2];
#pragma unroll
    for (int j = 0; j < 2; ++j)
        mk[j] = mask[b * 2048 + tj * 128 + wc * 64 + j * 32 + lm];

    __syncthreads();                  // all LDS reads of last tile done
    float* lrow_sum = lsum + b * 2048;
#pragma unroll
    for (int i = 0; i < 2; ++i) {
#pragma unroll
        for (int p = 0; p < 16; ++p) {
            int rloc = wr * 64 + i * 32 + (p & 3) + 8 * (p >> 2) + 4 * lg;
            int q = ti * 128 + rloc;
            float rs = 0.f;
#pragma unroll
            for (int j = 0; j < 2; ++j) {
                int n = tj * 128 + wc * 64 + j * 32 + lm;
                float pv = 0.f;
                if (n <= q && mk[j] != 0) pv = __expf(acc[i][j][p] * 0.03125f);
                rs += pv;
                shbuf[rloc * ETS + wc * 64 + j * 32 + lm] = f2bf(pv);
            }
            // reduce rs over the 32 lm lanes (lane bits 0..4)
#pragma unroll
            for (int o = 1; o <= 16; o <<= 1) rs += __shfl_xor(rs, o);
            if (lm == 0) atomicAdd(&lrow_sum[q], rs);
        }
    }
    __syncthreads();

    unsigned short* gbase = Pb + ((size_t)b * 2048 + ti * 128) * 2048 + tj * 128;
#pragma unroll
    for (int it = 0; it < 4; ++it) {
        int row = it * 32 + (tid >> 3), cc = tid & 7;
        uint4 v0 = *(const uint4*)(shbuf + row * ETS + cc * 8);
        uint4 v1 = *(const uint4*)(shbuf + row * ETS + 64 + cc * 8);
        *(uint4*)(gbase + (size_t)row * 2048 + cc * 8) = v0;
        *(uint4*)(gbase + (size_t)row * 2048 + 64 + cc * 8) = v1;
    }
}

// ---------------- kernel 4: O = (P' V) / l  (Pb bf16 ld=2048; Vt is [b][d][s]) -------------
// 512 blocks; complement-pair order: bids 0-255 get ti=15..8, 256-511 get ti=0..7,
// so co-resident long+short blocks balance per-CU load.
__global__ __launch_bounds__(256) void pv_gemm(const unsigned short* __restrict__ Pb,
                                               const unsigned short* __restrict__ Vt,
                                               const float* __restrict__ lsum,
                                               float* __restrict__ out) {
    int bid = blockIdx.x;            // 512 blocks
    int half = bid >> 8, rr = bid & 255;
    int tig = rr >> 5;               // 0..7
    int ti = half ? tig : 15 - tig;
    int dj = (rr >> 2) & 7;
    int b  = rr & 3;
    __shared__ unsigned short shbuf[2 * 128 * LSTR];
    unsigned short* Ash = shbuf;
    unsigned short* Bsh = shbuf + 128 * LSTR;
    int tid = threadIdx.x;
    int lane = tid & 63, w = tid >> 6, wr = w >> 1, wc = w & 1;
    floatx16 acc[2][2] = {{ACC_ZERO, ACC_ZERO}, {ACC_ZERO, ACC_ZERO}};

    const unsigned short* Ag = Pb + ((size_t)b * 2048 + ti * 128) * 2048;
    const unsigned short* Bg = Vt + ((size_t)b * 1024 + dj * 128) * 2048;
    int kend = (ti + 1) * 128;   // causal extent (Pb beyond this is never written/read)
    for (int k0 = 0; k0 < kend; k0 += BK) {
        __syncthreads();
        stage_async(Ash, Ag + k0, 2048, tid);
        stage_async(Bsh, Bg + k0, 2048, tid);
        __syncthreads();
        mfma_step(Ash, Bsh, lane, wr, wc, acc);
    }

    int lm = lane & 31, lg = lane >> 5;
#pragma unroll
    for (int i = 0; i < 2; ++i) {
#pragma unroll
        for (int g = 0; g < 4; ++g) {
            int qb = ti * 128 + wr * 64 + i * 32 + 8 * g + 4 * lg;
#pragma unroll
            for (int r = 0; r < 4; ++r) {
                float invl = 1.f / lsum[b * 2048 + qb + r];
#pragma unroll
                for (int j = 0; j < 2; ++j) {
                    int d = dj * 128 + wc * 64 + j * 32 + lm;
                    out[((size_t)b * 2048 + qb + r) * 1024 + d] = acc[i][j][4 * g + r] * invl;
                }
            }
        }
    }
}

// ---------------- launch ----------------
extern "C" void kernel_launch(void* const* d_in, const int* in_sizes, int n_in,
                              void* d_out, int out_size, void* d_ws, size_t ws_size,
                              hipStream_t stream) {
    const float* x    = (const float*)d_in[0];
    const int*   mask = (const int*)d_in[1];
    const float* wq   = (const float*)d_in[2];
    const float* wk   = (const float*)d_in[3];
    const float* wv   = (const float*)d_in[4];
    float* out = (float*)d_out;
    char* ws = (char*)d_ws;

    unsigned short* Xb = (unsigned short*)(ws + 0);           // 16 MiB  bf16 x
    unsigned short* Wb = (unsigned short*)(ws + 16777216);    //  6 MiB  bf16 Wq|Wk|Wv rows
    unsigned short* Qb = (unsigned short*)(ws + 23068672);    // 16 MiB  bf16 Q [8192,1024]
    unsigned short* Kb = (unsigned short*)(ws + 39845888);    // 16 MiB  bf16 K [8192,1024]
    unsigned short* Vt = (unsigned short*)(ws + 56623104);    // 16 MiB  bf16 V^T [4,1024,2048]
    unsigned short* Pb = (unsigned short*)(ws + 73400320);    // 32 MiB  bf16 P' [4,2048,2048]
    float*        lsum = (float*)(ws + 106954752);            // 32 KiB  fp32 row sums [8192]
    (void)ws_size; (void)in_sizes; (void)n_in; (void)out_size;

    cvt_kernel<<<11264, 256, 0, stream>>>(x, wq, wk, wv, Xb, Wb, lsum);
    qkv_gemm<<<dim3(32, 12), 512, 0, stream>>>(Xb, Wb, Qb, Kb, Vt);
    scores_gemm<<<dim3(136, 4), 256, 0, stream>>>(Qb, Kb, mask, Pb, lsum);
    pv_gemm<<<512, 256, 0, stream>>>(Pb, Vt, lsum, out);
}

// Round 3
// 229.099 us; speedup vs baseline: 1.0740x; 1.0740x over previous
//
#include <hip/hip_runtime.h>
#include <stdint.h>
#include <math.h>

// Problem constants: B=4, S=2048, D=1024
// Pipeline (4 dispatches): cvt(+zero l) -> qkv -> scores(exp epilogue + atomic rowsum)
//                          -> pv(normalize by 1/l).
// GEMM tile: 128x128 C-tile, BK=64, 256 threads (4 waves 2x2); per wave 64x64 via
// 2x2 MFMA 32x32x16_bf16. T3-minimum stage-ahead double-buffer in all three GEMMs —
// issue global_load_lds for tile t+1 BEFORE computing tile t, single __syncthreads
// per tile (its vmcnt(0) drain lands the prefetch; barrier publishes the buffer and
// retires all reads of the buffer being overwritten next iteration).
// LDS 64 KiB (2 blocks/CU); epilogues overlay the buffers (unchanged layout).
// NOTE: double-buffer pointers are computed per-iteration (shbuf + cur*TSH) — an
// LDS pointer ARRAY initializer is rejected by hipcc (addrspacecast in static init).
// LDS unpadded (global_load_lds writes base+lane*16); XOR chunk swizzle (cc ^ row&7)
// keeps fragment ds_reads conflict-free (verified: SQ_LDS_BANK_CONFLICT ~0 in loop).
#define BK 64
#define LSTR 64   // main-loop LDS row stride (bf16 elems)
#define ETS 132   // epilogue tile stride (128 + 4 pad)
#define TSH 8192  // one 128x64 bf16 tile in ushorts (16 KiB)

typedef __attribute__((ext_vector_type(8))) short short8;
typedef __attribute__((ext_vector_type(16))) float floatx16;

typedef __attribute__((address_space(3))) unsigned int lds_u32;
typedef const __attribute__((address_space(1))) unsigned int glb_u32;

__device__ __forceinline__ unsigned short f2bf(float f) {
    union { float f; unsigned u; } x; x.f = f;
    unsigned r = x.u + 0x7fffu + ((x.u >> 16) & 1u);  // RNE
    return (unsigned short)(r >> 16);
}

// ---------------- kernel 1: fp32 -> bf16 convert + zero the l[] accumulator ----------------
__global__ void cvt_kernel(const float* __restrict__ x,
                           const float* __restrict__ wq,
                           const float* __restrict__ wk,
                           const float* __restrict__ wv,
                           unsigned short* __restrict__ xb,
                           unsigned short* __restrict__ wb,
                           float* __restrict__ lsum) {
    int i4 = (blockIdx.x * 256 + threadIdx.x) * 4;   // total 11534336 elems, exact grid
    if (blockIdx.x < 8) {                            // zero l[8192] (atomic target in scores)
        float4 z = (float4){0.f, 0.f, 0.f, 0.f};
        *(float4*)(lsum + i4) = z;
    }
    const float* src; unsigned short* dst; int off;
    if (i4 < 8388608)       { src = x;  dst = xb;            off = i4; }
    else if (i4 < 9437184)  { src = wq; dst = wb;            off = i4 - 8388608; }
    else if (i4 < 10485760) { src = wk; dst = wb + 1048576;  off = i4 - 9437184; }
    else                    { src = wv; dst = wb + 2097152;  off = i4 - 10485760; }
    float4 v = *(const float4*)(src + off);
    ushort4 o;
    o.x = f2bf(v.x); o.y = f2bf(v.y); o.z = f2bf(v.z); o.w = f2bf(v.w);
    *(ushort4*)(dst + off) = o;
}

// ---------------- shared GEMM pieces ----------------
// async-stage a 128x64 bf16 tile (row-major, ld elems) into unpadded LDS with XOR
// swizzle: LDS chunk (row, cc) holds global chunk (row, cc ^ (row&7)).
__device__ __forceinline__ void stage_async(unsigned short* sh, const unsigned short* g,
                                            int ld, int tid) {
#pragma unroll
    for (int it = 0; it < 4; ++it) {
        int c = it * 256 + tid;          // 1024 chunks of 16B
        int row = c >> 3, cc = c & 7;
        int gcc = cc ^ (row & 7);
        __builtin_amdgcn_global_load_lds(
            (glb_u32*)(g + (size_t)row * ld + gcc * 8),
            (lds_u32*)(sh + c * 8), 16, 0, 0);
    }
}

// one BK=64 step: 8 MFMAs (32x32x16) per wave, 4 k-substeps of 16.
// A-frag: lane holds A[m = lane&31][k = (lane>>5)*8 + j]; B^T-pattern identical.
// Fragment reads un-swizzle the staging XOR.
__device__ __forceinline__ void mfma_step(const unsigned short* Ash, const unsigned short* Bsh,
                                          int lane, int wr, int wc, floatx16 acc[2][2]) {
    int lm = lane & 31, lg = lane >> 5;
#pragma unroll
    for (int h = 0; h < 4; ++h) {
        short8 af[2], bf[2];
#pragma unroll
        for (int i = 0; i < 2; ++i) {
            int ar = wr * 64 + i * 32 + lm;
            int br = wc * 64 + i * 32 + lm;
            af[i] = *(const short8*)(Ash + ar * LSTR + (((h << 1) | lg) ^ (ar & 7)) * 8);
            bf[i] = *(const short8*)(Bsh + br * LSTR + (((h << 1) | lg) ^ (br & 7)) * 8);
        }
#pragma unroll
        for (int i = 0; i < 2; ++i)
#pragma unroll
            for (int j = 0; j < 2; ++j)
                acc[i][j] = __builtin_amdgcn_mfma_f32_32x32x16_bf16(af[i], bf[j], acc[i][j], 0, 0, 0);
    }
}

#define ACC_ZERO {0.f,0.f,0.f,0.f,0.f,0.f,0.f,0.f,0.f,0.f,0.f,0.f,0.f,0.f,0.f,0.f}

// C/D layout (verified m74/m101): col = lane&31, row = (reg&3) + 8*(reg>>2) + 4*(lane>>5)

// ---------------- kernel 2: fused QKV projection GEMM ----------------
// C[m,n] = sum_k Xb[m,k] * Wb[n,k], m in [0,8192), n in [0,3072), K=1024
// n<1024 -> Q row-major, n<2048 -> K row-major, else V TRANSPOSED: Vt[b][d][s].
// Epilogue goes through LDS for coalesced 16B stores.
__global__ __launch_bounds__(256) void qkv_gemm(const unsigned short* __restrict__ Xb,
                                                const unsigned short* __restrict__ Wb,
                                                unsigned short* __restrict__ Qb,
                                                unsigned short* __restrict__ Kb,
                                                unsigned short* __restrict__ Vt) {
    // [A0][A1][B0][B1] each 16 KiB = 64 KiB; epilogue overlays the front 33 KiB
    __shared__ unsigned short shbuf[4 * TSH];
    int tid = threadIdx.x;
    int bm = blockIdx.x, bn = blockIdx.y;
    int lane = tid & 63, w = tid >> 6, wr = w >> 1, wc = w & 1;
    floatx16 acc[2][2] = {{ACC_ZERO, ACC_ZERO}, {ACC_ZERO, ACC_ZERO}};

    const unsigned short* Ag = Xb + (size_t)bm * 128 * 1024;
    const unsigned short* Bg = Wb + (size_t)bn * 128 * 1024;
    stage_async(shbuf, Ag, 1024, tid);
    stage_async(shbuf + 2 * TSH, Bg, 1024, tid);
    __syncthreads();                      // vmcnt(0) drain + publish tile 0
#pragma unroll 2
    for (int t = 0; t < 16; ++t) {
        int cur = t & 1;
        unsigned short* Ash = shbuf + cur * TSH;
        unsigned short* Bsh = shbuf + (2 + cur) * TSH;
        if (t < 15) {                     // stage-ahead: loads fly under the MFMA phase
            stage_async(shbuf + (cur ^ 1) * TSH, Ag + (t + 1) * BK, 1024, tid);
            stage_async(shbuf + (2 + (cur ^ 1)) * TSH, Bg + (t + 1) * BK, 1024, tid);
        }
        mfma_step(Ash, Bsh, lane, wr, wc, acc);
        __syncthreads();                  // drains prefetch + retires reads of buf cur
    }

    int which = bn >> 3;              // 0=Q 1=K 2=V
    int nnb = (bn & 7) * 128;
    int lm = lane & 31, lg = lane >> 5;
    if (which < 2) {
        // row-major [m_local][n_local]
#pragma unroll
        for (int i = 0; i < 2; ++i)
#pragma unroll
            for (int j = 0; j < 2; ++j)
#pragma unroll
                for (int p = 0; p < 16; ++p) {
                    int row = wr * 64 + i * 32 + (p & 3) + 8 * (p >> 2) + 4 * lg;
                    shbuf[row * ETS + wc * 64 + j * 32 + lm] = f2bf(acc[i][j][p]);
                }
    } else {
        // transposed [n_local][m_local]: regs 4g..4g+3 are 4 consecutive rows -> ushort4
#pragma unroll
        for (int i = 0; i < 2; ++i)
#pragma unroll
            for (int j = 0; j < 2; ++j)
#pragma unroll
                for (int g = 0; g < 4; ++g) {
                    int mb = wr * 64 + i * 32 + 8 * g + 4 * lg;
                    ushort4 o;
                    o.x = f2bf(acc[i][j][4 * g + 0]); o.y = f2bf(acc[i][j][4 * g + 1]);
                    o.z = f2bf(acc[i][j][4 * g + 2]); o.w = f2bf(acc[i][j][4 * g + 3]);
                    *(ushort4*)(shbuf + (wc * 64 + j * 32 + lm) * ETS + mb) = o;
                }
    }
    __syncthreads();

    unsigned short* gbase; size_t gld;
    if (which == 0)      { gbase = Qb + (size_t)(bm * 128) * 1024 + nnb; gld = 1024; }
    else if (which == 1) { gbase = Kb + (size_t)(bm * 128) * 1024 + nnb; gld = 1024; }
    else { gbase = Vt + ((size_t)(bm >> 4) * 1024 + nnb) * 2048 + (bm & 15) * 128; gld = 2048; }
#pragma unroll
    for (int it = 0; it < 4; ++it) {
        int row = it * 32 + (tid >> 3), cc = tid & 7;
        uint4 v0 = *(const uint4*)(shbuf + row * ETS + cc * 8);
        uint4 v1 = *(const uint4*)(shbuf + row * ETS + 64 + cc * 8);
        *(uint4*)(gbase + (size_t)row * gld + cc * 8) = v0;
        *(uint4*)(gbase + (size_t)row * gld + 64 + cc * 8) = v1;
    }
}

// ---------------- kernel 3: P' = exp((Q K^T)/32) masked, bf16, + row sums l[] --------------
// Lower-tri tiles only; unnormalized exp (|s| <~ 8 so fp32-safe, softmax is shift-invariant).
__global__ __launch_bounds__(256) void scores_gemm(const unsigned short* __restrict__ Qb,
                                                   const unsigned short* __restrict__ Kb,
                                                   const int* __restrict__ mask,
                                                   unsigned short* __restrict__ Pb,
                                                   float* __restrict__ lsum) {
    int u = blockIdx.x, b = blockIdx.y;
    int ti = (int)((sqrtf(8.0f * (float)u + 1.0f) - 1.0f) * 0.5f);
    while ((ti + 1) * (ti + 2) / 2 <= u) ti++;
    while (ti * (ti + 1) / 2 > u) ti--;
    int tj = u - ti * (ti + 1) / 2;

    __shared__ unsigned short shbuf[4 * TSH];
    int tid = threadIdx.x;
    int lane = tid & 63, w = tid >> 6, wr = w >> 1, wc = w & 1;
    floatx16 acc[2][2] = {{ACC_ZERO, ACC_ZERO}, {ACC_ZERO, ACC_ZERO}};

    const unsigned short* Ag = Qb + ((size_t)b * 2048 + ti * 128) * 1024;
    const unsigned short* Bg = Kb + ((size_t)b * 2048 + tj * 128) * 1024;
    stage_async(shbuf, Ag, 1024, tid);
    stage_async(shbuf + 2 * TSH, Bg, 1024, tid);
    __syncthreads();
#pragma unroll 2
    for (int t = 0; t < 16; ++t) {
        int cur = t & 1;
        unsigned short* Ash = shbuf + cur * TSH;
        unsigned short* Bsh = shbuf + (2 + cur) * TSH;
        if (t < 15) {
            stage_async(shbuf + (cur ^ 1) * TSH, Ag + (t + 1) * BK, 1024, tid);
            stage_async(shbuf + (2 + (cur ^ 1)) * TSH, Bg + (t + 1) * BK, 1024, tid);
        }
        mfma_step(Ash, Bsh, lane, wr, wc, acc);
        __syncthreads();
    }

    int lm = lane & 31, lg = lane >> 5;
    int mk[2];
#pragma unroll
    for (int j = 0; j < 2; ++j)
        mk[j] = mask[b * 2048 + tj * 128 + wc * 64 + j * 32 + lm];

    float* lrow_sum = lsum + b * 2048;
#pragma unroll
    for (int i = 0; i < 2; ++i) {
#pragma unroll
        for (int p = 0; p < 16; ++p) {
            int rloc = wr * 64 + i * 32 + (p & 3) + 8 * (p >> 2) + 4 * lg;
            int q = ti * 128 + rloc;
            float rs = 0.f;
#pragma unroll
            for (int j = 0; j < 2; ++j) {
                int n = tj * 128 + wc * 64 + j * 32 + lm;
                float pv = 0.f;
                if (n <= q && mk[j] != 0) pv = __expf(acc[i][j][p] * 0.03125f);
                rs += pv;
                shbuf[rloc * ETS + wc * 64 + j * 32 + lm] = f2bf(pv);
            }
            // reduce rs over the 32 lm lanes (lane bits 0..4)
#pragma unroll
            for (int o = 1; o <= 16; o <<= 1) rs += __shfl_xor(rs, o);
            if (lm == 0) atomicAdd(&lrow_sum[q], rs);
        }
    }
    __syncthreads();

    unsigned short* gbase = Pb + ((size_t)b * 2048 + ti * 128) * 2048 + tj * 128;
#pragma unroll
    for (int it = 0; it < 4; ++it) {
        int row = it * 32 + (tid >> 3), cc = tid & 7;
        uint4 v0 = *(const uint4*)(shbuf + row * ETS + cc * 8);
        uint4 v1 = *(const uint4*)(shbuf + row * ETS + 64 + cc * 8);
        *(uint4*)(gbase + (size_t)row * 2048 + cc * 8) = v0;
        *(uint4*)(gbase + (size_t)row * 2048 + 64 + cc * 8) = v1;
    }
}

// ---------------- kernel 4: O = (P' V) / l  (Pb bf16 ld=2048; Vt is [b][d][s]) -------------
// 512 blocks at 64 KiB LDS -> exactly 2 resident/CU; complement-pair order: bids 0-255
// get ti=15..8, 256-511 get ti=0..7, so co-resident pairs sum to uniform 17 tiles/CU.
__global__ __launch_bounds__(256) void pv_gemm(const unsigned short* __restrict__ Pb,
                                               const unsigned short* __restrict__ Vt,
                                               const float* __restrict__ lsum,
                                               float* __restrict__ out) {
    int bid = blockIdx.x;            // 512 blocks
    int half = bid >> 8, rr = bid & 255;
    int tig = rr >> 5;               // 0..7
    int ti = half ? tig : 15 - tig;
    int dj = (rr >> 2) & 7;
    int b  = rr & 3;
    __shared__ unsigned short shbuf[4 * TSH];
    int tid = threadIdx.x;
    int lane = tid & 63, w = tid >> 6, wr = w >> 1, wc = w & 1;
    floatx16 acc[2][2] = {{ACC_ZERO, ACC_ZERO}, {ACC_ZERO, ACC_ZERO}};

    const unsigned short* Ag = Pb + ((size_t)b * 2048 + ti * 128) * 2048;
    const unsigned short* Bg = Vt + ((size_t)b * 1024 + dj * 128) * 2048;
    int nt = (ti + 1) * 2;           // causal extent in BK=64 tiles (always even)
    stage_async(shbuf, Ag, 2048, tid);
    stage_async(shbuf + 2 * TSH, Bg, 2048, tid);
    __syncthreads();
    for (int t = 0; t < nt; ++t) {
        int cur = t & 1;
        unsigned short* Ash = shbuf + cur * TSH;
        unsigned short* Bsh = shbuf + (2 + cur) * TSH;
        if (t + 1 < nt) {
            stage_async(shbuf + (cur ^ 1) * TSH, Ag + (t + 1) * BK, 2048, tid);
            stage_async(shbuf + (2 + (cur ^ 1)) * TSH, Bg + (t + 1) * BK, 2048, tid);
        }
        mfma_step(Ash, Bsh, lane, wr, wc, acc);
        __syncthreads();
    }

    int lm = lane & 31, lg = lane >> 5;
#pragma unroll
    for (int i = 0; i < 2; ++i) {
#pragma unroll
        for (int g = 0; g < 4; ++g) {
            int qb = ti * 128 + wr * 64 + i * 32 + 8 * g + 4 * lg;
#pragma unroll
            for (int r = 0; r < 4; ++r) {
                float invl = 1.f / lsum[b * 2048 + qb + r];
#pragma unroll
                for (int j = 0; j < 2; ++j) {
                    int d = dj * 128 + wc * 64 + j * 32 + lm;
                    out[((size_t)b * 2048 + qb + r) * 1024 + d] = acc[i][j][4 * g + r] * invl;
                }
            }
        }
    }
}

// ---------------- launch ----------------
extern "C" void kernel_launch(void* const* d_in, const int* in_sizes, int n_in,
                              void* d_out, int out_size, void* d_ws, size_t ws_size,
                              hipStream_t stream) {
    const float* x    = (const float*)d_in[0];
    const int*   mask = (const int*)d_in[1];
    const float* wq   = (const float*)d_in[2];
    const float* wk   = (const float*)d_in[3];
    const float* wv   = (const float*)d_in[4];
    float* out = (float*)d_out;
    char* ws = (char*)d_ws;

    unsigned short* Xb = (unsigned short*)(ws + 0);           // 16 MiB  bf16 x
    unsigned short* Wb = (unsigned short*)(ws + 16777216);    //  6 MiB  bf16 Wq|Wk|Wv rows
    unsigned short* Qb = (unsigned short*)(ws + 23068672);    // 16 MiB  bf16 Q [8192,1024]
    unsigned short* Kb = (unsigned short*)(ws + 39845888);    // 16 MiB  bf16 K [8192,1024]
    unsigned short* Vt = (unsigned short*)(ws + 56623104);    // 16 MiB  bf16 V^T [4,1024,2048]
    unsigned short* Pb = (unsigned short*)(ws + 73400320);    // 32 MiB  bf16 P' [4,2048,2048]
    float*        lsum = (float*)(ws + 106954752);            // 32 KiB  fp32 row sums [8192]
    (void)ws_size; (void)in_sizes; (void)n_in; (void)out_size;

    cvt_kernel<<<11264, 256, 0, stream>>>(x, wq, wk, wv, Xb, Wb, lsum);
    qkv_gemm<<<dim3(64, 24), 256, 0, stream>>>(Xb, Wb, Qb, Kb, Vt);
    scores_gemm<<<dim3(136, 4), 256, 0, stream>>>(Qb, Kb, mask, Pb, lsum);
    pv_gemm<<<512, 256, 0, stream>>>(Pb, Vt, lsum, out);
}

// Round 4
// 221.763 us; speedup vs baseline: 1.1096x; 1.0331x over previous
//
#include <hip/hip_runtime.h>
#include <stdint.h>
#include <math.h>

// Problem constants: B=4, S=2048, D=1024
// Pipeline (4 dispatches): cvt(+zero l) -> qkv -> scores(exp epilogue + atomic rowsum)
//                          -> pv(normalize by 1/l).
// GEMM tile: 128x128 C-tile, 256 threads (4 waves 2x2); per wave 64x64 via
// 2x2 MFMA 32x32x16_bf16, stage-ahead double-buffer (global_load_lds for tile t+1
// issued BEFORE computing tile t, single __syncthreads per tile).
// qkv/pv: BK=64 (LDS 64 KiB, 2 blocks/CU).
// scores: BK=32 (4 x 8 KiB staging, LDS 33.8 KiB incl. epilogue overlay -> 4 blocks/CU)
//   so all 544 blocks are resident in ONE round (at 64 KiB only 512 fit -> 2nd round tail).
//   BK=32 swizzle key is (row>>1)&3 (4 chunks/row): 8 consecutive rows cover all 32 banks
//   exactly once (16*(r&1) + 4*(chunk^key)) — same conflict-freedom as BK=64's (row&7).
// LDS unpadded (global_load_lds writes base+lane*16); XOR chunk swizzle applied on the
// global SOURCE address and un-done on the fragment ds_read (same involution).
#define BK 64
#define LSTR 64   // BK=64 LDS row stride (bf16 elems)
#define ETS 132   // epilogue tile stride (128 + 4 pad)
#define TSH 8192  // one 128x64 bf16 tile in ushorts (16 KiB)
#define TSH32 4096 // one 128x32 bf16 tile in ushorts (8 KiB)

typedef __attribute__((ext_vector_type(8))) short short8;
typedef __attribute__((ext_vector_type(16))) float floatx16;

typedef __attribute__((address_space(3))) unsigned int lds_u32;
typedef const __attribute__((address_space(1))) unsigned int glb_u32;

__device__ __forceinline__ unsigned short f2bf(float f) {
    union { float f; unsigned u; } x; x.f = f;
    unsigned r = x.u + 0x7fffu + ((x.u >> 16) & 1u);  // RNE
    return (unsigned short)(r >> 16);
}

// ---------------- kernel 1: fp32 -> bf16 convert + zero the l[] accumulator ----------------
__global__ void cvt_kernel(const float* __restrict__ x,
                           const float* __restrict__ wq,
                           const float* __restrict__ wk,
                           const float* __restrict__ wv,
                           unsigned short* __restrict__ xb,
                           unsigned short* __restrict__ wb,
                           float* __restrict__ lsum) {
    int i4 = (blockIdx.x * 256 + threadIdx.x) * 4;   // total 11534336 elems, exact grid
    if (blockIdx.x < 8) {                            // zero l[8192] (atomic target in scores)
        float4 z = (float4){0.f, 0.f, 0.f, 0.f};
        *(float4*)(lsum + i4) = z;
    }
    const float* src; unsigned short* dst; int off;
    if (i4 < 8388608)       { src = x;  dst = xb;            off = i4; }
    else if (i4 < 9437184)  { src = wq; dst = wb;            off = i4 - 8388608; }
    else if (i4 < 10485760) { src = wk; dst = wb + 1048576;  off = i4 - 9437184; }
    else                    { src = wv; dst = wb + 2097152;  off = i4 - 10485760; }
    float4 v = *(const float4*)(src + off);
    ushort4 o;
    o.x = f2bf(v.x); o.y = f2bf(v.y); o.z = f2bf(v.z); o.w = f2bf(v.w);
    *(ushort4*)(dst + off) = o;
}

// ---------------- shared GEMM pieces (BK=64) ----------------
// async-stage a 128x64 bf16 tile (row-major, ld elems) into unpadded LDS with XOR
// swizzle: LDS chunk (row, cc) holds global chunk (row, cc ^ (row&7)).
__device__ __forceinline__ void stage_async(unsigned short* sh, const unsigned short* g,
                                            int ld, int tid) {
#pragma unroll
    for (int it = 0; it < 4; ++it) {
        int c = it * 256 + tid;          // 1024 chunks of 16B
        int row = c >> 3, cc = c & 7;
        int gcc = cc ^ (row & 7);
        __builtin_amdgcn_global_load_lds(
            (glb_u32*)(g + (size_t)row * ld + gcc * 8),
            (lds_u32*)(sh + c * 8), 16, 0, 0);
    }
}

// one BK=64 step: 16 MFMAs (32x32x16) per wave, 4 k-substeps of 16.
// A-frag: lane holds A[m = lane&31][k = (lane>>5)*8 + j]; B^T-pattern identical.
// Fragment reads un-swizzle the staging XOR.
__device__ __forceinline__ void mfma_step(const unsigned short* Ash, const unsigned short* Bsh,
                                          int lane, int wr, int wc, floatx16 acc[2][2]) {
    int lm = lane & 31, lg = lane >> 5;
#pragma unroll
    for (int h = 0; h < 4; ++h) {
        short8 af[2], bf[2];
#pragma unroll
        for (int i = 0; i < 2; ++i) {
            int ar = wr * 64 + i * 32 + lm;
            int br = wc * 64 + i * 32 + lm;
            af[i] = *(const short8*)(Ash + ar * LSTR + (((h << 1) | lg) ^ (ar & 7)) * 8);
            bf[i] = *(const short8*)(Bsh + br * LSTR + (((h << 1) | lg) ^ (br & 7)) * 8);
        }
#pragma unroll
        for (int i = 0; i < 2; ++i)
#pragma unroll
            for (int j = 0; j < 2; ++j)
                acc[i][j] = __builtin_amdgcn_mfma_f32_32x32x16_bf16(af[i], bf[j], acc[i][j], 0, 0, 0);
    }
}

// ---------------- BK=32 variants (scores): 4 chunks/row, swizzle key (row>>1)&3 -----------
__device__ __forceinline__ void stage_async32(unsigned short* sh, const unsigned short* g,
                                              int ld, int tid) {
#pragma unroll
    for (int it = 0; it < 2; ++it) {
        int c = it * 256 + tid;          // 512 chunks of 16B
        int row = c >> 2, cc = c & 3;
        int gcc = cc ^ ((row >> 1) & 3);
        __builtin_amdgcn_global_load_lds(
            (glb_u32*)(g + (size_t)row * ld + gcc * 8),
            (lds_u32*)(sh + c * 8), 16, 0, 0);
    }
}

__device__ __forceinline__ void mfma_step32(const unsigned short* Ash, const unsigned short* Bsh,
                                            int lane, int wr, int wc, floatx16 acc[2][2]) {
    int lm = lane & 31, lg = lane >> 5;
#pragma unroll
    for (int h = 0; h < 2; ++h) {
        short8 af[2], bf[2];
#pragma unroll
        for (int i = 0; i < 2; ++i) {
            int ar = wr * 64 + i * 32 + lm;
            int br = wc * 64 + i * 32 + lm;
            af[i] = *(const short8*)(Ash + ar * 32 + ((((h << 1) | lg) ^ ((ar >> 1) & 3)) * 8));
            bf[i] = *(const short8*)(Bsh + br * 32 + ((((h << 1) | lg) ^ ((br >> 1) & 3)) * 8));
        }
#pragma unroll
        for (int i = 0; i < 2; ++i)
#pragma unroll
            for (int j = 0; j < 2; ++j)
                acc[i][j] = __builtin_amdgcn_mfma_f32_32x32x16_bf16(af[i], bf[j], acc[i][j], 0, 0, 0);
    }
}

#define ACC_ZERO {0.f,0.f,0.f,0.f,0.f,0.f,0.f,0.f,0.f,0.f,0.f,0.f,0.f,0.f,0.f,0.f}

// C/D layout (verified m74/m101): col = lane&31, row = (reg&3) + 8*(reg>>2) + 4*(lane>>5)

// ---------------- kernel 2: fused QKV projection GEMM ----------------
// C[m,n] = sum_k Xb[m,k] * Wb[n,k], m in [0,8192), n in [0,3072), K=1024
// n<1024 -> Q row-major, n<2048 -> K row-major, else V TRANSPOSED: Vt[b][d][s].
// Epilogue goes through LDS for coalesced 16B stores.
__global__ __launch_bounds__(256) void qkv_gemm(const unsigned short* __restrict__ Xb,
                                                const unsigned short* __restrict__ Wb,
                                                unsigned short* __restrict__ Qb,
                                                unsigned short* __restrict__ Kb,
                                                unsigned short* __restrict__ Vt) {
    // [A0][A1][B0][B1] each 16 KiB = 64 KiB; epilogue overlays the front 33 KiB
    __shared__ unsigned short shbuf[4 * TSH];
    int tid = threadIdx.x;
    int bm = blockIdx.x, bn = blockIdx.y;
    int lane = tid & 63, w = tid >> 6, wr = w >> 1, wc = w & 1;
    floatx16 acc[2][2] = {{ACC_ZERO, ACC_ZERO}, {ACC_ZERO, ACC_ZERO}};

    const unsigned short* Ag = Xb + (size_t)bm * 128 * 1024;
    const unsigned short* Bg = Wb + (size_t)bn * 128 * 1024;
    stage_async(shbuf, Ag, 1024, tid);
    stage_async(shbuf + 2 * TSH, Bg, 1024, tid);
    __syncthreads();                      // vmcnt(0) drain + publish tile 0
#pragma unroll 2
    for (int t = 0; t < 16; ++t) {
        int cur = t & 1;
        unsigned short* Ash = shbuf + cur * TSH;
        unsigned short* Bsh = shbuf + (2 + cur) * TSH;
        if (t < 15) {                     // stage-ahead: loads fly under the MFMA phase
            stage_async(shbuf + (cur ^ 1) * TSH, Ag + (t + 1) * BK, 1024, tid);
            stage_async(shbuf + (2 + (cur ^ 1)) * TSH, Bg + (t + 1) * BK, 1024, tid);
        }
        mfma_step(Ash, Bsh, lane, wr, wc, acc);
        __syncthreads();                  // drains prefetch + retires reads of buf cur
    }

    int which = bn >> 3;              // 0=Q 1=K 2=V
    int nnb = (bn & 7) * 128;
    int lm = lane & 31, lg = lane >> 5;
    if (which < 2) {
        // row-major [m_local][n_local]
#pragma unroll
        for (int i = 0; i < 2; ++i)
#pragma unroll
            for (int j = 0; j < 2; ++j)
#pragma unroll
                for (int p = 0; p < 16; ++p) {
                    int row = wr * 64 + i * 32 + (p & 3) + 8 * (p >> 2) + 4 * lg;
                    shbuf[row * ETS + wc * 64 + j * 32 + lm] = f2bf(acc[i][j][p]);
                }
    } else {
        // transposed [n_local][m_local]: regs 4g..4g+3 are 4 consecutive rows -> ushort4
#pragma unroll
        for (int i = 0; i < 2; ++i)
#pragma unroll
            for (int j = 0; j < 2; ++j)
#pragma unroll
                for (int g = 0; g < 4; ++g) {
                    int mb = wr * 64 + i * 32 + 8 * g + 4 * lg;
                    ushort4 o;
                    o.x = f2bf(acc[i][j][4 * g + 0]); o.y = f2bf(acc[i][j][4 * g + 1]);
                    o.z = f2bf(acc[i][j][4 * g + 2]); o.w = f2bf(acc[i][j][4 * g + 3]);
                    *(ushort4*)(shbuf + (wc * 64 + j * 32 + lm) * ETS + mb) = o;
                }
    }
    __syncthreads();

    unsigned short* gbase; size_t gld;
    if (which == 0)      { gbase = Qb + (size_t)(bm * 128) * 1024 + nnb; gld = 1024; }
    else if (which == 1) { gbase = Kb + (size_t)(bm * 128) * 1024 + nnb; gld = 1024; }
    else { gbase = Vt + ((size_t)(bm >> 4) * 1024 + nnb) * 2048 + (bm & 15) * 128; gld = 2048; }
#pragma unroll
    for (int it = 0; it < 4; ++it) {
        int row = it * 32 + (tid >> 3), cc = tid & 7;
        uint4 v0 = *(const uint4*)(shbuf + row * ETS + cc * 8);
        uint4 v1 = *(const uint4*)(shbuf + row * ETS + 64 + cc * 8);
        *(uint4*)(gbase + (size_t)row * gld + cc * 8) = v0;
        *(uint4*)(gbase + (size_t)row * gld + 64 + cc * 8) = v1;
    }
}

// ---------------- kernel 3: P' = exp((Q K^T)/32) masked, bf16, + row sums l[] --------------
// Lower-tri tiles only; unnormalized exp (|s| <~ 8 so fp32-safe, softmax is shift-invariant).
// BK=32 + 33.8 KiB LDS -> 4 blocks/CU -> all 544 blocks resident in one round.
__global__ __launch_bounds__(256) void scores_gemm(const unsigned short* __restrict__ Qb,
                                                   const unsigned short* __restrict__ Kb,
                                                   const int* __restrict__ mask,
                                                   unsigned short* __restrict__ Pb,
                                                   float* __restrict__ lsum) {
    int u = blockIdx.x, b = blockIdx.y;
    int ti = (int)((sqrtf(8.0f * (float)u + 1.0f) - 1.0f) * 0.5f);
    while ((ti + 1) * (ti + 2) / 2 <= u) ti++;
    while (ti * (ti + 1) / 2 > u) ti--;
    int tj = u - ti * (ti + 1) / 2;

    // epilogue overlay (128*ETS = 16896 ushorts) >= 4 staging tiles (16384 ushorts)
    __shared__ unsigned short shbuf[128 * ETS];
    int tid = threadIdx.x;
    int lane = tid & 63, w = tid >> 6, wr = w >> 1, wc = w & 1;
    floatx16 acc[2][2] = {{ACC_ZERO, ACC_ZERO}, {ACC_ZERO, ACC_ZERO}};

    const unsigned short* Ag = Qb + ((size_t)b * 2048 + ti * 128) * 1024;
    const unsigned short* Bg = Kb + ((size_t)b * 2048 + tj * 128) * 1024;
    stage_async32(shbuf, Ag, 1024, tid);
    stage_async32(shbuf + 2 * TSH32, Bg, 1024, tid);
    __syncthreads();
#pragma unroll 2
    for (int t = 0; t < 32; ++t) {
        int cur = t & 1;
        unsigned short* Ash = shbuf + cur * TSH32;
        unsigned short* Bsh = shbuf + (2 + cur) * TSH32;
        if (t < 31) {
            stage_async32(shbuf + (cur ^ 1) * TSH32, Ag + (t + 1) * 32, 1024, tid);
            stage_async32(shbuf + (2 + (cur ^ 1)) * TSH32, Bg + (t + 1) * 32, 1024, tid);
        }
        mfma_step32(Ash, Bsh, lane, wr, wc, acc);
        __syncthreads();
    }

    int lm = lane & 31, lg = lane >> 5;
    int mk[2];
#pragma unroll
    for (int j = 0; j < 2; ++j)
        mk[j] = mask[b * 2048 + tj * 128 + wc * 64 + j * 32 + lm];

    float* lrow_sum = lsum + b * 2048;
#pragma unroll
    for (int i = 0; i < 2; ++i) {
#pragma unroll
        for (int p = 0; p < 16; ++p) {
            int rloc = wr * 64 + i * 32 + (p & 3) + 8 * (p >> 2) + 4 * lg;
            int q = ti * 128 + rloc;
            float rs = 0.f;
#pragma unroll
            for (int j = 0; j < 2; ++j) {
                int n = tj * 128 + wc * 64 + j * 32 + lm;
                float pv = 0.f;
                if (n <= q && mk[j] != 0) pv = __expf(acc[i][j][p] * 0.03125f);
                rs += pv;
                shbuf[rloc * ETS + wc * 64 + j * 32 + lm] = f2bf(pv);
            }
            // reduce rs over the 32 lm lanes (lane bits 0..4)
#pragma unroll
            for (int o = 1; o <= 16; o <<= 1) rs += __shfl_xor(rs, o);
            if (lm == 0) atomicAdd(&lrow_sum[q], rs);
        }
    }
    __syncthreads();

    unsigned short* gbase = Pb + ((size_t)b * 2048 + ti * 128) * 2048 + tj * 128;
#pragma unroll
    for (int it = 0; it < 4; ++it) {
        int row = it * 32 + (tid >> 3), cc = tid & 7;
        uint4 v0 = *(const uint4*)(shbuf + row * ETS + cc * 8);
        uint4 v1 = *(const uint4*)(shbuf + row * ETS + 64 + cc * 8);
        *(uint4*)(gbase + (size_t)row * 2048 + cc * 8) = v0;
        *(uint4*)(gbase + (size_t)row * 2048 + 64 + cc * 8) = v1;
    }
}

// ---------------- kernel 4: O = (P' V) / l  (Pb bf16 ld=2048; Vt is [b][d][s]) -------------
// 512 blocks at 64 KiB LDS -> exactly 2 resident/CU; complement-pair order: bids 0-255
// get ti=15..8, 256-511 get ti=0..7, so co-resident pairs sum to uniform 17 tiles/CU.
__global__ __launch_bounds__(256) void pv_gemm(const unsigned short* __restrict__ Pb,
                                               const unsigned short* __restrict__ Vt,
                                               const float* __restrict__ lsum,
                                               float* __restrict__ out) {
    int bid = blockIdx.x;            // 512 blocks
    int half = bid >> 8, rr = bid & 255;
    int tig = rr >> 5;               // 0..7
    int ti = half ? tig : 15 - tig;
    int dj = (rr >> 2) & 7;
    int b  = rr & 3;
    __shared__ unsigned short shbuf[4 * TSH];
    int tid = threadIdx.x;
    int lane = tid & 63, w = tid >> 6, wr = w >> 1, wc = w & 1;
    floatx16 acc[2][2] = {{ACC_ZERO, ACC_ZERO}, {ACC_ZERO, ACC_ZERO}};

    const unsigned short* Ag = Pb + ((size_t)b * 2048 + ti * 128) * 2048;
    const unsigned short* Bg = Vt + ((size_t)b * 1024 + dj * 128) * 2048;
    int nt = (ti + 1) * 2;           // causal extent in BK=64 tiles (always even)
    stage_async(shbuf, Ag, 2048, tid);
    stage_async(shbuf + 2 * TSH, Bg, 2048, tid);
    __syncthreads();
    for (int t = 0; t < nt; ++t) {
        int cur = t & 1;
        unsigned short* Ash = shbuf + cur * TSH;
        unsigned short* Bsh = shbuf + (2 + cur) * TSH;
        if (t + 1 < nt) {
            stage_async(shbuf + (cur ^ 1) * TSH, Ag + (t + 1) * BK, 2048, tid);
            stage_async(shbuf + (2 + (cur ^ 1)) * TSH, Bg + (t + 1) * BK, 2048, tid);
        }
        mfma_step(Ash, Bsh, lane, wr, wc, acc);
        __syncthreads();
    }

    int lm = lane & 31, lg = lane >> 5;
#pragma unroll
    for (int i = 0; i < 2; ++i) {
#pragma unroll
        for (int g = 0; g < 4; ++g) {
            int qb = ti * 128 + wr * 64 + i * 32 + 8 * g + 4 * lg;
#pragma unroll
            for (int r = 0; r < 4; ++r) {
                float invl = 1.f / lsum[b * 2048 + qb + r];
#pragma unroll
                for (int j = 0; j < 2; ++j) {
                    int d = dj * 128 + wc * 64 + j * 32 + lm;
                    out[((size_t)b * 2048 + qb + r) * 1024 + d] = acc[i][j][4 * g + r] * invl;
                }
            }
        }
    }
}

// ---------------- launch ----------------
extern "C" void kernel_launch(void* const* d_in, const int* in_sizes, int n_in,
                              void* d_out, int out_size, void* d_ws, size_t ws_size,
                              hipStream_t stream) {
    const float* x    = (const float*)d_in[0];
    const int*   mask = (const int*)d_in[1];
    const float* wq   = (const float*)d_in[2];
    const float* wk   = (const float*)d_in[3];
    const float* wv   = (const float*)d_in[4];
    float* out = (float*)d_out;
    char* ws = (char*)d_ws;

    unsigned short* Xb = (unsigned short*)(ws + 0);           // 16 MiB  bf16 x
    unsigned short* Wb = (unsigned short*)(ws + 16777216);    //  6 MiB  bf16 Wq|Wk|Wv rows
    unsigned short* Qb = (unsigned short*)(ws + 23068672);    // 16 MiB  bf16 Q [8192,1024]
    unsigned short* Kb = (unsigned short*)(ws + 39845888);    // 16 MiB  bf16 K [8192,1024]
    unsigned short* Vt = (unsigned short*)(ws + 56623104);    // 16 MiB  bf16 V^T [4,1024,2048]
    unsigned short* Pb = (unsigned short*)(ws + 73400320);    // 32 MiB  bf16 P' [4,2048,2048]
    float*        lsum = (float*)(ws + 106954752);            // 32 KiB  fp32 row sums [8192]
    (void)ws_size; (void)in_sizes; (void)n_in; (void)out_size;

    cvt_kernel<<<11264, 256, 0, stream>>>(x, wq, wk, wv, Xb, Wb, lsum);
    qkv_gemm<<<dim3(64, 24), 256, 0, stream>>>(Xb, Wb, Qb, Kb, Vt);
    scores_gemm<<<dim3(136, 4), 256, 0, stream>>>(Qb, Kb, mask, Pb, lsum);
    pv_gemm<<<512, 256, 0, stream>>>(Pb, Vt, lsum, out);
}